// Round 2
// baseline (2153.579 us; speedup 1.0000x reference)
//
#include <hip/hip_runtime.h>
#include <hip/hip_bf16.h>

#define NN 10000
#define EE 320000

typedef __attribute__((ext_vector_type(8))) short bf8_t;   // 8 bf16 (4 VGPR)
typedef __attribute__((ext_vector_type(4))) short s4_t;
typedef __attribute__((ext_vector_type(4))) float f4_t;

__device__ __forceinline__ float b2f(short b){
  union { unsigned u; float f; } v; v.u = ((unsigned)(unsigned short)b) << 16; return v.f;
}
__device__ __forceinline__ short f2b(float f){
  union { float f; unsigned u; } v; v.f = f;
  unsigned r = (v.u + 0x7fffu + ((v.u >> 16) & 1u)) >> 16;
  return (short)r;
}

// staging loaders: 8 contiguous elements -> bf16x8
__device__ __forceinline__ bf8_t load8(const short* p){ return *(const bf8_t*)p; }
__device__ __forceinline__ bf8_t load8(const float* p){
  float4 a = ((const float4*)p)[0], b = ((const float4*)p)[1];
  bf8_t o;
  o[0]=f2b(a.x); o[1]=f2b(a.y); o[2]=f2b(a.z); o[3]=f2b(a.w);
  o[4]=f2b(b.x); o[5]=f2b(b.y); o[6]=f2b(b.z); o[7]=f2b(b.w);
  return o;
}

// ---------------- weight transpose+convert: fusion weights ----------------
__global__ void prep_fusion(const float* __restrict__ sw, const float* __restrict__ ew,
                            const float* __restrict__ gw,
                            short* __restrict__ structT, short* __restrict__ esmT,
                            short* __restrict__ gateT){
  int idx = blockIdx.x * 256 + threadIdx.x;
  if (idx < 256*64){ int o = idx/64, k = idx - o*64; structT[idx] = f2b(sw[k*256+o]); return; }
  idx -= 256*64;
  if (idx < 256*1280){ int o = idx/1280, k = idx - o*1280; esmT[idx] = f2b(ew[k*256+o]); return; }
  idx -= 256*1280;
  if (idx < 256*512){ int o = idx/512, k = idx - o*512; gateT[idx] = f2b(gw[k*256+o]); return; }
}

// ---------------- per-layer weight prep (single-layer buffers) ----------------
// EW1T [512 out][256 in] from edge_w1 rows 0..511 (src part cols 0..255, dst 256..511)
// W2T/Wc1T [256][256]; NW1T [256 out][768 in] (h | agg_hi | agg_lo share rows 256..511)
__global__ void prep_layer(const float* __restrict__ ew1, const float* __restrict__ ew2,
                           const float* __restrict__ cw1, const float* __restrict__ nw1,
                           short* __restrict__ EW1T, short* __restrict__ W2T,
                           short* __restrict__ Wc1T, short* __restrict__ NW1T){
  int idx = blockIdx.x * 256 + threadIdx.x;
  if (idx < 512*256){
    int o = idx >> 8, k = idx & 255;
    float v = (o < 256) ? ew1[k*256 + o] : ew1[(256 + k)*256 + (o - 256)];
    EW1T[idx] = f2b(v); return;
  } idx -= 512*256;
  if (idx < 65536){ int o = idx >> 8, k = idx & 255; W2T[idx] = f2b(ew2[k*256+o]); return; } idx -= 65536;
  if (idx < 65536){ int o = idx >> 8, k = idx & 255; Wc1T[idx] = f2b(cw1[k*256+o]); return; } idx -= 65536;
  if (idx < 256*768){
    int o = idx/768, k = idx - o*768;
    int kk = (k < 512) ? k : (k - 256);
    NW1T[idx] = f2b(nw1[kk*256 + o]);
  }
}

// ---------------- generic bf16 MFMA GEMM: C = [relu](A@WT^T + bias) ----------------
// A [M,K] (f32 or bf16) row-major w/ leading dim lda, WT [NC,K] bf16.
// grid (ceil(M/64), NC/256), block 256 (4 waves, each 64x64 of the 64x256 tile).
template<bool RELU, typename AT>
__global__ __launch_bounds__(256, 2) void gemm_bf16(
    const AT* __restrict__ A, const int K, const int lda, const short* __restrict__ WT,
    const float* __restrict__ bias, const int M,
    float* __restrict__ outF, const int ldf,
    short* __restrict__ outB, const int ldb)
{
  __shared__ __align__(16) short at[64*40];   // 64 rows x 32 k, stride 40 (bank-conflict pad)
  const int tid = threadIdx.x;
  const int w = tid >> 6, l = tid & 63;
  const int g = l >> 4, cl = l & 15;
  const int m0 = blockIdx.x * 64;
  const int cb = blockIdx.y * 256 + w * 64;
  const f4_t fz = {0.f, 0.f, 0.f, 0.f};
  f4_t acc[4][4];
#pragma unroll
  for (int fr = 0; fr < 4; fr++)
#pragma unroll
    for (int cf = 0; cf < 4; cf++) acc[fr][cf] = fz;
  const int r = tid >> 2, kq = tid & 3;
  for (int k0 = 0; k0 < K; k0 += 32){
    bf8_t av = {0,0,0,0,0,0,0,0};
    if (m0 + r < M) av = load8(A + (size_t)(m0 + r)*lda + k0 + kq*8);
    *(bf8_t*)(&at[r*40 + kq*8]) = av;
    __syncthreads();
    bf8_t bfr[4], afr[4];
#pragma unroll
    for (int cf = 0; cf < 4; cf++)
      bfr[cf] = *(const bf8_t*)(WT + (size_t)(cb + cf*16 + cl)*K + k0 + 8*g);
#pragma unroll
    for (int fr = 0; fr < 4; fr++)
      afr[fr] = *(const bf8_t*)(&at[(fr*16 + cl)*40 + 8*g]);
#pragma unroll
    for (int fr = 0; fr < 4; fr++)
#pragma unroll
      for (int cf = 0; cf < 4; cf++)
        acc[fr][cf] = __builtin_amdgcn_mfma_f32_16x16x32_bf16(afr[fr], bfr[cf], acc[fr][cf], 0, 0, 0);
    __syncthreads();
  }
#pragma unroll
  for (int fr = 0; fr < 4; fr++){
#pragma unroll
    for (int cf = 0; cf < 4; cf++){
      const int col = cb + cf*16 + cl;
      const float bv = bias ? bias[col] : 0.f;
#pragma unroll
      for (int j = 0; j < 4; j++){
        const int row = m0 + fr*16 + 4*g + j;
        if (row < M){
          float v = acc[fr][cf][j] + bv;
          if (RELU) v = fmaxf(v, 0.f);
          if (outF) outF[(size_t)row*ldf + col] = v;
          if (outB) outB[(size_t)row*ldb + col] = f2b(v);
        }
      }
    }
  }
}

// ---------------- gate GEMM with fused dot-product reduction ----------------
// A = hb [N,512] bf16; z[row] = sum_col relu(A@gateT^T + b1)[col] * gw2[col]
__global__ __launch_bounds__(256, 2) void gate_gemm(
    const short* __restrict__ A, const short* __restrict__ WT,
    const float* __restrict__ bias, const float* __restrict__ gw2,
    float* __restrict__ gatez)
{
  __shared__ __align__(16) short at[64*40];
  __shared__ float psum[4][64];
  const int K = 512;
  const int tid = threadIdx.x;
  const int w = tid >> 6, l = tid & 63;
  const int g = l >> 4, cl = l & 15;
  const int m0 = blockIdx.x * 64;
  const int cb = w * 64;
  const f4_t fz = {0.f,0.f,0.f,0.f};
  f4_t acc[4][4];
#pragma unroll
  for (int fr = 0; fr < 4; fr++)
#pragma unroll
    for (int cf = 0; cf < 4; cf++) acc[fr][cf] = fz;
  const int r = tid >> 2, kq = tid & 3;
  for (int k0 = 0; k0 < K; k0 += 32){
    bf8_t av = {0,0,0,0,0,0,0,0};
    if (m0 + r < NN) av = *(const bf8_t*)(A + (size_t)(m0 + r)*K + k0 + kq*8);
    *(bf8_t*)(&at[r*40 + kq*8]) = av;
    __syncthreads();
    bf8_t bfr[4], afr[4];
#pragma unroll
    for (int cf = 0; cf < 4; cf++)
      bfr[cf] = *(const bf8_t*)(WT + (size_t)(cb + cf*16 + cl)*K + k0 + 8*g);
#pragma unroll
    for (int fr = 0; fr < 4; fr++)
      afr[fr] = *(const bf8_t*)(&at[(fr*16 + cl)*40 + 8*g]);
#pragma unroll
    for (int fr = 0; fr < 4; fr++)
#pragma unroll
      for (int cf = 0; cf < 4; cf++)
        acc[fr][cf] = __builtin_amdgcn_mfma_f32_16x16x32_bf16(afr[fr], bfr[cf], acc[fr][cf], 0, 0, 0);
    __syncthreads();
  }
#pragma unroll
  for (int fr = 0; fr < 4; fr++){
    float s1[4] = {0,0,0,0};
#pragma unroll
    for (int cf = 0; cf < 4; cf++){
      const int col = cb + cf*16 + cl;
      const float bv = bias[col], wv = gw2[col];
#pragma unroll
      for (int j = 0; j < 4; j++) s1[j] += fmaxf(acc[fr][cf][j] + bv, 0.f) * wv;
    }
#pragma unroll
    for (int j = 0; j < 4; j++){
      for (int m = 1; m < 16; m <<= 1) s1[j] += __shfl_xor(s1[j], m);
    }
    if (cl == 0){
#pragma unroll
      for (int j = 0; j < 4; j++) psum[w][fr*16 + 4*g + j] = s1[j];
    }
  }
  __syncthreads();
  if (tid < 64 && m0 + tid < NN)
    gatez[m0 + tid] = psum[0][tid] + psum[1][tid] + psum[2][tid] + psum[3][tid];
}

// ---------------- node update GEMM with fused residual + LayerNorm ----------------
// hb2 [N,768] bf16 (h | agg_hi | agg_lo) is BOTH input and (cols 0..255) output.
__global__ __launch_bounds__(256, 2) void ln_gemm(
    short* hb2, const short* __restrict__ WT,
    const float* __restrict__ bias, const float* __restrict__ gamma, const float* __restrict__ beta,
    float* hf32)
{
  __shared__ __align__(16) short at[64*40];
  __shared__ float psum[4][64], psq[4][64];
  __shared__ float mu_s[64], rs_s[64];
  const int K = 768;
  const int tid = threadIdx.x;
  const int w = tid >> 6, l = tid & 63;
  const int g = l >> 4, cl = l & 15;
  const int m0 = blockIdx.x * 64;
  const int cb = w * 64;
  const f4_t fz = {0.f,0.f,0.f,0.f};
  f4_t acc[4][4];
#pragma unroll
  for (int fr = 0; fr < 4; fr++)
#pragma unroll
    for (int cf = 0; cf < 4; cf++) acc[fr][cf] = fz;
  const int r = tid >> 2, kq = tid & 3;
  for (int k0 = 0; k0 < K; k0 += 32){
    bf8_t av = {0,0,0,0,0,0,0,0};
    if (m0 + r < NN) av = *(const bf8_t*)(hb2 + (size_t)(m0 + r)*K + k0 + kq*8);
    *(bf8_t*)(&at[r*40 + kq*8]) = av;
    __syncthreads();
    bf8_t bfr[4], afr[4];
#pragma unroll
    for (int cf = 0; cf < 4; cf++)
      bfr[cf] = *(const bf8_t*)(WT + (size_t)(cb + cf*16 + cl)*K + k0 + 8*g);
#pragma unroll
    for (int fr = 0; fr < 4; fr++)
      afr[fr] = *(const bf8_t*)(&at[(fr*16 + cl)*40 + 8*g]);
#pragma unroll
    for (int fr = 0; fr < 4; fr++)
#pragma unroll
      for (int cf = 0; cf < 4; cf++)
        acc[fr][cf] = __builtin_amdgcn_mfma_f32_16x16x32_bf16(afr[fr], bfr[cf], acc[fr][cf], 0, 0, 0);
    __syncthreads();
  }
  // y = h_old + relu(acc + bias)
#pragma unroll
  for (int fr = 0; fr < 4; fr++){
#pragma unroll
    for (int cf = 0; cf < 4; cf++){
      const int col = cb + cf*16 + cl;
      const float bv = bias[col];
#pragma unroll
      for (int j = 0; j < 4; j++){
        const int row = m0 + fr*16 + 4*g + j;
        const float hold = (row < NN) ? hf32[(size_t)row*256 + col] : 0.f;
        acc[fr][cf][j] = hold + fmaxf(acc[fr][cf][j] + bv, 0.f);
      }
    }
  }
  // row stats
#pragma unroll
  for (int fr = 0; fr < 4; fr++){
    float s1[4] = {0,0,0,0}, s2[4] = {0,0,0,0};
#pragma unroll
    for (int cf = 0; cf < 4; cf++)
#pragma unroll
      for (int j = 0; j < 4; j++){ float v = acc[fr][cf][j]; s1[j] += v; s2[j] += v*v; }
#pragma unroll
    for (int j = 0; j < 4; j++){
      for (int m = 1; m < 16; m <<= 1){ s1[j] += __shfl_xor(s1[j], m); s2[j] += __shfl_xor(s2[j], m); }
    }
    if (cl == 0){
#pragma unroll
      for (int j = 0; j < 4; j++){ psum[w][fr*16 + 4*g + j] = s1[j]; psq[w][fr*16 + 4*g + j] = s2[j]; }
    }
  }
  __syncthreads();
  if (tid < 64){
    float s = psum[0][tid] + psum[1][tid] + psum[2][tid] + psum[3][tid];
    float q = psq[0][tid] + psq[1][tid] + psq[2][tid] + psq[3][tid];
    float mu = s * (1.f/256.f);
    float var = q * (1.f/256.f) - mu*mu;
    mu_s[tid] = mu; rs_s[tid] = rsqrtf(var + 1e-5f);
  }
  __syncthreads();
#pragma unroll
  for (int fr = 0; fr < 4; fr++){
#pragma unroll
    for (int cf = 0; cf < 4; cf++){
      const int col = cb + cf*16 + cl;
#pragma unroll
      for (int j = 0; j < 4; j++){
        const int rl = fr*16 + 4*g + j;
        const int row = m0 + rl;
        if (row < NN){
          float v = (acc[fr][cf][j] - mu_s[rl]) * rs_s[rl] * gamma[col] + beta[col];
          hf32[(size_t)row*256 + col] = v;
          hb2[(size_t)row*768 + col] = f2b(v);
        }
      }
    }
  }
}

// ---------------- fully-fused per-layer edge kernel ----------------
__global__ __launch_bounds__(256, 2) void edge_kernel(
    const int* __restrict__ eidx, const float* __restrict__ eattr,
    const float* __restrict__ cpos, const short* __restrict__ Abuf,
    const float* __restrict__ wd, const float* __restrict__ We, const float* __restrict__ b1,
    const short* __restrict__ W2T, const float* __restrict__ b2,
    const short* __restrict__ Wc1T, const float* __restrict__ bc1,
    const float* __restrict__ wc2, const float* __restrict__ bc2,
    float* __restrict__ agg, float* __restrict__ pos_delta)
{
  __shared__ __align__(16) short mt[64*264];
  __shared__ __align__(16) float ea_s[64][16];
  __shared__ int sidx[64], didx[64];
  __shared__ float d2_s[64];
  __shared__ float dir_s[64][3];
  __shared__ float cpart[4][64];
  const int tid = threadIdx.x;
  const int w = tid >> 6, l = tid & 63;
  const int g = l >> 4, cl = l & 15;
  const int e0 = blockIdx.x * 64;
  if (tid < 64){
    const int e = e0 + tid;
    const int s = eidx[e], d = eidx[EE + e];
    sidx[tid] = s; didx[tid] = d;
    const float dx = cpos[d*3+0] - cpos[s*3+0];
    const float dy = cpos[d*3+1] - cpos[s*3+1];
    const float dz = cpos[d*3+2] - cpos[s*3+2];
    float d2 = dx*dx + dy*dy + dz*dz;
    d2 = fminf(d2, 1000.f);
    const float inv = rsqrtf(d2 + 1e-8f);
    d2_s[tid] = d2;
    dir_s[tid][0] = dx*inv; dir_s[tid][1] = dy*inv; dir_s[tid][2] = dz*inv;
  }
  ((float4*)ea_s)[tid] = ((const float4*)(eattr + (size_t)e0*16))[tid];
  __syncthreads();
  // phase 1: assemble m1 (thread owns column c = tid)
  {
    const int c = tid;
    const float wd_c = wd[c], b1_c = b1[c];
    float wec[16];
#pragma unroll
    for (int j = 0; j < 16; j++) wec[j] = We[j*256 + c];
#pragma unroll 4
    for (int e = 0; e < 64; e++){
      const int s = sidx[e], d = didx[e];
      float v = b2f(Abuf[(size_t)s*512 + c]) + b2f(Abuf[(size_t)d*512 + 256 + c]) + d2_s[e]*wd_c + b1_c;
      float ad = 0.f;
#pragma unroll
      for (int j = 0; j < 16; j++) ad += ea_s[e][j] * wec[j];
      v = fmaxf(v + ad, 0.f);
      mt[e*264 + c] = f2b(v);
    }
  }
  __syncthreads();
  const int cb = w * 64;
  const f4_t fz = {0.f,0.f,0.f,0.f};
  // GEMM1: m = relu(m1 @ W2 + b2)
  f4_t a1[4][4];
#pragma unroll
  for (int fr = 0; fr < 4; fr++)
#pragma unroll
    for (int cf = 0; cf < 4; cf++) a1[fr][cf] = fz;
  for (int k0 = 0; k0 < 256; k0 += 32){
    bf8_t bfr[4], afr[4];
#pragma unroll
    for (int cf = 0; cf < 4; cf++)
      bfr[cf] = *(const bf8_t*)(W2T + (size_t)(cb + cf*16 + cl)*256 + k0 + 8*g);
#pragma unroll
    for (int fr = 0; fr < 4; fr++)
      afr[fr] = *(const bf8_t*)(&mt[(fr*16 + cl)*264 + k0 + 8*g]);
#pragma unroll
    for (int fr = 0; fr < 4; fr++)
#pragma unroll
      for (int cf = 0; cf < 4; cf++)
        a1[fr][cf] = __builtin_amdgcn_mfma_f32_16x16x32_bf16(afr[fr], bfr[cf], a1[fr][cf], 0, 0, 0);
  }
  __syncthreads();
  {
    float b2v[4];
#pragma unroll
    for (int cf = 0; cf < 4; cf++) b2v[cf] = b2[cb + cf*16 + cl];
#pragma unroll
    for (int fr = 0; fr < 4; fr++)
#pragma unroll
      for (int cf = 0; cf < 4; cf++)
#pragma unroll
        for (int j = 0; j < 4; j++){
          const float v = fmaxf(a1[fr][cf][j] + b2v[cf], 0.f);
          const int row = fr*16 + 4*g + j;
          const int col = cb + cf*16 + cl;
          mt[row*264 + col] = f2b(v);
          atomicAdd(&agg[(size_t)didx[row]*256 + col], v);
        }
  }
  __syncthreads();
  // GEMM2: u = relu(m @ Wc1 + bc1); c = tanh(sum(u*wc2)+bc2)*0.1
  f4_t a2[4][4];
#pragma unroll
  for (int fr = 0; fr < 4; fr++)
#pragma unroll
    for (int cf = 0; cf < 4; cf++) a2[fr][cf] = fz;
  for (int k0 = 0; k0 < 256; k0 += 32){
    bf8_t bfr[4], afr[4];
#pragma unroll
    for (int cf = 0; cf < 4; cf++)
      bfr[cf] = *(const bf8_t*)(Wc1T + (size_t)(cb + cf*16 + cl)*256 + k0 + 8*g);
#pragma unroll
    for (int fr = 0; fr < 4; fr++)
      afr[fr] = *(const bf8_t*)(&mt[(fr*16 + cl)*264 + k0 + 8*g]);
#pragma unroll
    for (int fr = 0; fr < 4; fr++)
#pragma unroll
      for (int cf = 0; cf < 4; cf++)
        a2[fr][cf] = __builtin_amdgcn_mfma_f32_16x16x32_bf16(afr[fr], bfr[cf], a2[fr][cf], 0, 0, 0);
  }
  {
    float bc1v[4], wc2v[4];
#pragma unroll
    for (int cf = 0; cf < 4; cf++){
      const int col = cb + cf*16 + cl;
      bc1v[cf] = bc1[col]; wc2v[cf] = wc2[col];
    }
#pragma unroll
    for (int fr = 0; fr < 4; fr++){
      float rs[4] = {0,0,0,0};
#pragma unroll
      for (int cf = 0; cf < 4; cf++)
#pragma unroll
        for (int j = 0; j < 4; j++)
          rs[j] += fmaxf(a2[fr][cf][j] + bc1v[cf], 0.f) * wc2v[cf];
#pragma unroll
      for (int j = 0; j < 4; j++){
        for (int m = 1; m < 16; m <<= 1) rs[j] += __shfl_xor(rs[j], m);
      }
      if (cl == 0){
#pragma unroll
        for (int j = 0; j < 4; j++) cpart[w][fr*16 + 4*g + j] = rs[j];
      }
    }
  }
  __syncthreads();
  if (tid < 64){
    const float cp = cpart[0][tid] + cpart[1][tid] + cpart[2][tid] + cpart[3][tid] + bc2[0];
    const float cc = tanhf(cp) * 0.1f;
    const int d = didx[tid];
    atomicAdd(&pos_delta[d*3+0], dir_s[tid][0]*cc);
    atomicAdd(&pos_delta[d*3+1], dir_s[tid][1]*cc);
    atomicAdd(&pos_delta[d*3+2], dir_s[tid][2]*cc);
  }
}

// ---------------- fusion gate/mix (one wave per node) ----------------
// hf32 holds h_struct f32 on entry (written by struct GEMM); overwritten with h.
__global__ void fusion_mix(const float* __restrict__ gatez,
                           const float* __restrict__ gb2,
                           const float* __restrict__ s1p, const float* __restrict__ s2p,
                           const float* __restrict__ hef,
                           const float* __restrict__ pos,
                           float* hf32, short* __restrict__ hb2,
                           float* __restrict__ cur_pos, float* __restrict__ pos_delta,
                           float* __restrict__ agg)
{
  const int node = blockIdx.x * 4 + (threadIdx.x >> 6);
  const int l = threadIdx.x & 63;
  if (node >= NN) return;
  const float z = gatez[node] + gb2[0];
  const float gt = 1.f / (1.f + expf(-z));
  const float a = gt * s1p[0], b = (1.f - gt) * s2p[0];
#pragma unroll
  for (int k = 0; k < 4; k++){
    const int c = l + 64*k;
    const float hv = fmaxf(a*hf32[(size_t)node*256 + c] + b*hef[(size_t)node*256 + c], 0.f);
    hf32[(size_t)node*256 + c] = hv;
    hb2[(size_t)node*768 + c] = f2b(hv);
    agg[(size_t)node*256 + c] = 0.f;
  }
  if (l < 3){ cur_pos[node*3 + l] = pos[node*3 + l]; pos_delta[node*3 + l] = 0.f; }
}

// ---------------- between layers: pos update, agg -> bf16 hi/lo, re-zero ----------------
__global__ void interlayer(float* __restrict__ agg, short* __restrict__ hb2,
                           float* __restrict__ cur_pos, float* __restrict__ pos_delta)
{
  const int n = blockIdx.x;
  const int c = threadIdx.x;
  const float a = agg[(size_t)n*256 + c];
  const short hi = f2b(a);
  const float lo = a - b2f(hi);
  hb2[(size_t)n*768 + 256 + c] = hi;
  hb2[(size_t)n*768 + 512 + c] = f2b(lo);
  agg[(size_t)n*256 + c] = 0.f;
  if (c < 3){ cur_pos[n*3 + c] += pos_delta[n*3 + c]; pos_delta[n*3 + c] = 0.f; }
}

// ---------------- final LN + head (one wave per node) ----------------
__global__ void head_kernel(const float* __restrict__ hf32,
                            const float* __restrict__ fg, const float* __restrict__ fb,
                            const float* __restrict__ hw, const float* __restrict__ hbias,
                            float* __restrict__ out)
{
  const int node = blockIdx.x * 4 + (threadIdx.x >> 6);
  const int l = threadIdx.x & 63;
  if (node >= NN) return;
  float x[4], s = 0.f, q = 0.f;
#pragma unroll
  for (int k = 0; k < 4; k++){ x[k] = hf32[(size_t)node*256 + l + 64*k]; s += x[k]; q += x[k]*x[k]; }
#pragma unroll
  for (int m = 1; m < 64; m <<= 1){ s += __shfl_xor(s, m); q += __shfl_xor(q, m); }
  const float mu = s * (1.f/256.f);
  const float var = q * (1.f/256.f) - mu*mu;
  const float rs = rsqrtf(var + 1e-5f);
  float xn[4];
#pragma unroll
  for (int k = 0; k < 4; k++){ const int c = l + 64*k; xn[k] = (x[k]-mu)*rs*fg[c] + fb[c]; }
  for (int o = 0; o < 20; o++){
    float p = 0.f;
#pragma unroll
    for (int k = 0; k < 4; k++) p += xn[k] * hw[(l + 64*k)*20 + o];
#pragma unroll
    for (int m = 1; m < 64; m <<= 1) p += __shfl_xor(p, m);
    if (l == 0) out[node*20 + o] = p + hbias[o];
  }
}

extern "C" void kernel_launch(void* const* d_in, const int* in_sizes, int n_in,
                              void* d_out, int out_size, void* d_ws, size_t ws_size,
                              hipStream_t stream)
{
  (void)in_sizes; (void)n_in; (void)out_size; (void)ws_size;
  const float* x_struct = (const float*)d_in[0];
  const float* x_esm    = (const float*)d_in[1];
  const int*   eidx     = (const int*)d_in[2];
  const float* eattr    = (const float*)d_in[3];
  const float* pos      = (const float*)d_in[4];
  const float* struct_w = (const float*)d_in[5];
  const float* struct_b = (const float*)d_in[6];
  const float* esm_w    = (const float*)d_in[7];
  const float* esm_b    = (const float*)d_in[8];
  const float* gate_w1  = (const float*)d_in[9];
  const float* gate_b1  = (const float*)d_in[10];
  const float* gate_w2  = (const float*)d_in[11];
  const float* gate_b2  = (const float*)d_in[12];
  const float* s_scale  = (const float*)d_in[13];
  const float* e_scale  = (const float*)d_in[14];
  const float* edge_w1  = (const float*)d_in[15];
  const float* edge_b1  = (const float*)d_in[16];
  const float* edge_w2  = (const float*)d_in[17];
  const float* edge_b2  = (const float*)d_in[18];
  const float* coord_w1 = (const float*)d_in[19];
  const float* coord_b1 = (const float*)d_in[20];
  const float* coord_w2 = (const float*)d_in[21];
  const float* coord_b2 = (const float*)d_in[22];
  const float* node_w1  = (const float*)d_in[23];
  const float* node_b1  = (const float*)d_in[24];
  const float* ln_g     = (const float*)d_in[25];
  const float* ln_b     = (const float*)d_in[26];
  const float* fn_g     = (const float*)d_in[27];
  const float* fn_b     = (const float*)d_in[28];
  const float* head_w   = (const float*)d_in[29];
  const float* head_b   = (const float*)d_in[30];

  char* ws = (char*)d_ws;
  size_t off = 0;
  auto alloc = [&](size_t b){ size_t r = off; off += (b + 255) & ~(size_t)255; return r; };
  // ~48 MB total workspace
  float* hf32 = (float*)(ws + alloc((size_t)NN*256*4));   // h f32; pre-fusion: h_struct f32
  char* agghb = ws + alloc((size_t)NN*512*2);             // agg f32[N,256] / hb bf16[N,512]
  float* agg  = (float*)agghb;
  short* hb   = (short*)agghb;
  float* cpos = (float*)(ws + alloc((size_t)NN*3*4));
  float* pdel = (float*)(ws + alloc((size_t)NN*3*4));
  float* gatez= (float*)(ws + alloc((size_t)NN*4));
  short* hb2  = (short*)(ws + alloc((size_t)NN*768*2));   // h bf16 | agg_hi | agg_lo
  char* AbufR = ws + alloc((size_t)NN*512*2);             // Abuf bf16[N,512] / hef f32[N,256]
  short* Abuf = (short*)AbufR;
  float* hef  = (float*)AbufR;
  short* structT = (short*)(ws + alloc(256*64*2));
  short* esmT    = (short*)(ws + alloc(256*1280*2));
  short* gateT   = (short*)(ws + alloc(256*512*2));
  short* EW1T    = (short*)(ws + alloc((size_t)512*256*2));
  short* W2T     = (short*)(ws + alloc((size_t)256*256*2));
  short* Wc1T    = (short*)(ws + alloc((size_t)256*256*2));
  short* NW1T    = (short*)(ws + alloc((size_t)256*768*2));

  prep_fusion<<<dim3(1856), 256, 0, stream>>>(struct_w, esm_w, gate_w1, structT, esmT, gateT);

  gemm_bf16<false,float><<<dim3(157,1), 256, 0, stream>>>(x_struct, 64, 64, structT, struct_b, NN,
                                                          hf32, 256, hb, 512);
  gemm_bf16<false,float><<<dim3(157,1), 256, 0, stream>>>(x_esm, 1280, 1280, esmT, esm_b, NN,
                                                          hef, 256, hb + 256, 512);
  gate_gemm<<<dim3(157), 256, 0, stream>>>(hb, gateT, gate_b1, gate_w2, gatez);
  fusion_mix<<<dim3(2500), 256, 0, stream>>>(gatez, gate_b2, s_scale, e_scale, hef, pos,
                                             hf32, hb2, cpos, pdel, agg);
  for (int i = 0; i < 4; i++){
    prep_layer<<<dim3(1792), 256, 0, stream>>>(
        edge_w1 + (size_t)i*529*256, edge_w2 + (size_t)i*256*256,
        coord_w1 + (size_t)i*256*256, node_w1 + (size_t)i*512*256,
        EW1T, W2T, Wc1T, NW1T);
    gemm_bf16<false,short><<<dim3(157,2), 256, 0, stream>>>(hb2, 256, 768, EW1T, nullptr, NN,
                                                            nullptr, 0, Abuf, 512);
    edge_kernel<<<dim3(5000), 256, 0, stream>>>(eidx, eattr, cpos, Abuf,
        edge_w1 + (size_t)i*529*256 + 512*256,      // wd row
        edge_w1 + (size_t)i*529*256 + 513*256,      // We [16][256]
        edge_b1 + (size_t)i*256,
        W2T, edge_b2 + (size_t)i*256,
        Wc1T, coord_b1 + (size_t)i*256,
        coord_w2 + (size_t)i*256, coord_b2 + i,
        agg, pdel);
    interlayer<<<dim3(NN), 256, 0, stream>>>(agg, hb2, cpos, pdel);
    ln_gemm<<<dim3(157), 256, 0, stream>>>(hb2, NW1T, node_b1 + (size_t)i*256,
                                           ln_g + (size_t)i*256, ln_b + (size_t)i*256, hf32);
  }
  head_kernel<<<dim3(2500), 256, 0, stream>>>(hf32, fn_g, fn_b, head_w, head_b, (float*)d_out);
}